// Round 5
// baseline (360.095 us; speedup 1.0000x reference)
//
#include <hip/hip_runtime.h>
#include <math.h>

typedef __attribute__((ext_vector_type(4))) float f32x4;
typedef __attribute__((ext_vector_type(8))) short bf16x8;
typedef __attribute__((ext_vector_type(2))) unsigned int uint2v;
typedef __attribute__((ext_vector_type(4))) unsigned int uint4v;

#define LOG2E 1.4426950408889634f
#define MT 32

static __device__ __forceinline__ unsigned short f2bf(float f) {
  union { float f; unsigned int i; } u; u.f = f;
  unsigned int r = u.i + 0x7fffu + ((u.i >> 16) & 1u);   // RNE
  return (unsigned short)(r >> 16);
}
static __device__ __forceinline__ float bf2f(unsigned short s) {
  union { unsigned int i; float f; } u; u.i = ((unsigned int)s) << 16;
  return u.f;
}

// ---------------- kernel 0: transpose first-layer weights [32][256] -> [256][32]
__global__ __launch_bounds__(256) void k_wprep(const float* __restrict__ w1a,
                                               const float* __restrict__ w2a,
                                               float* __restrict__ w1aT,
                                               float* __restrict__ w2aT) {
  int i = blockIdx.x * 256 + threadIdx.x;
  if (i < 32 * 256) {
    int o = i >> 8, c = i & 255;
    w1aT[c * 32 + o] = w1a[i];
    w2aT[c * 32 + o] = w2a[i];
  }
}

// ---------------- kernel 0b: F -> Fbf [c][n] and FbfT [n][c] (bf16)
// block = (b, cg, ng): 64c x 64n tile. 1024 blocks x 256 thr.
__global__ __launch_bounds__(256) void k_cvt(const float* __restrict__ F,
                                             unsigned short* __restrict__ Fbf,
                                             unsigned short* __restrict__ FbfT) {
  __shared__ unsigned short Lt[64][68];
  const int bi = blockIdx.x;
  const int b = bi >> 8, cg = (bi >> 6) & 3, ng = bi & 63;
  const int tid = threadIdx.x;
  {
    const int cl = tid >> 2, part = tid & 3;
    const size_t row = (size_t)(b * 256 + cg * 64 + cl);
    const float* src = F + row * 4096 + ng * 64 + part * 16;
    unsigned int pk[8];
#pragma unroll
    for (int i = 0; i < 4; ++i) {
      f32x4 v = *(const f32x4*)(src + i * 4);
      pk[2 * i]     = (unsigned int)f2bf(v[0]) | ((unsigned int)f2bf(v[1]) << 16);
      pk[2 * i + 1] = (unsigned int)f2bf(v[2]) | ((unsigned int)f2bf(v[3]) << 16);
    }
    unsigned short* dst = Fbf + row * 4096 + ng * 64 + part * 16;
    uint4v a = {pk[0], pk[1], pk[2], pk[3]};
    uint4v c2 = {pk[4], pk[5], pk[6], pk[7]};
    *(uint4v*)(dst) = a;
    *(uint4v*)(dst + 8) = c2;
    unsigned short* lrow = &Lt[cl][part * 16];
#pragma unroll
    for (int i = 0; i < 8; ++i) {
      lrow[2 * i]     = (unsigned short)(pk[i] & 0xffffu);
      lrow[2 * i + 1] = (unsigned short)(pk[i] >> 16);
    }
  }
  __syncthreads();
  {
    const int nl = tid & 63, ch = tid >> 6;   // ch: 32-channel half-chunk (4)
    unsigned int pk[16];
#pragma unroll
    for (int i = 0; i < 16; ++i) {
      unsigned short a = Lt[ch * 16 + 0 + (i >> 3) * 8 + 0][nl]; // placeholder
      pk[i] = 0; (void)a;
    }
    // (re-done below properly)
    unsigned short vals[16];
#pragma unroll
    for (int i = 0; i < 16; ++i) vals[i] = Lt[ch * 16 + i][nl];
#pragma unroll
    for (int i = 0; i < 8; ++i)
      pk[i] = (unsigned int)vals[2 * i] | ((unsigned int)vals[2 * i + 1] << 16);
    unsigned short* dst = FbfT + ((size_t)(b * 4096 + ng * 64 + nl)) * 256 + cg * 64 + ch * 16;
    uint4v v0 = {pk[0], pk[1], pk[2], pk[3]};
    uint4v v1 = {pk[4], pk[5], pk[6], pk[7]};
    *(uint4v*)(dst) = v0;
    *(uint4v*)(dst + 8) = v1;
  }
}

// ---------------- kernel 1: q/k projections from FbfT, fp32 weights
// grid 2048 x 64 thr: block = (path, 16-px tile). lane = (px=l>>2, cq=l&3).
__global__ __launch_bounds__(64) void k_qk(
    const unsigned short* __restrict__ FbfT,
    const float* __restrict__ w1aT, const float* __restrict__ b1a,
    const float* __restrict__ w1b,  const float* __restrict__ b1b,
    const float* __restrict__ w2aT, const float* __restrict__ b2a,
    const float* __restrict__ w2b,  const float* __restrict__ b2b,
    unsigned short* __restrict__ qT, unsigned short* __restrict__ kT) {
  const int p = blockIdx.x & 1;
  const int tile = blockIdx.x >> 1;
  const int l = threadIdx.x;
  const int px = l >> 2, cq = l & 3;
  const int n = tile * 16 + px;          // flat b*4096+n
  const float* wA = p ? w2aT : w1aT;
  const float* bA = p ? b2a : b1a;
  const float* wB = p ? w2b : w1b;
  const float* bB = p ? b2b : b1b;

  bf16x8 f8[8];
  {
    const unsigned short* src = FbfT + (size_t)n * 256 + cq * 64;
#pragma unroll
    for (int i = 0; i < 8; ++i) f8[i] = *(const bf16x8*)(src + i * 8);
  }
  float h[32];
#pragma unroll
  for (int o = 0; o < 32; ++o) h[o] = 0.f;

#pragma unroll
  for (int i = 0; i < 8; ++i) {
    bf16x8 v = f8[i];
#pragma unroll
    for (int jj = 0; jj < 8; ++jj) {
      float fv = bf2f((unsigned short)v[jj]);
      const float* wr = wA + (size_t)(cq * 64 + i * 8 + jj) * 32;
#pragma unroll
      for (int o4 = 0; o4 < 8; ++o4) {
        f32x4 wv = *(const f32x4*)(wr + o4 * 4);
        h[o4 * 4 + 0] += wv[0] * fv;
        h[o4 * 4 + 1] += wv[1] * fv;
        h[o4 * 4 + 2] += wv[2] * fv;
        h[o4 * 4 + 3] += wv[3] * fv;
      }
    }
  }
  // quad reduce (lanes share px; cq 0..3 are lanes l^1, l^2)
#pragma unroll
  for (int o = 0; o < 32; ++o) {
    float t = h[o];
    t += __shfl_xor(t, 1);
    t += __shfl_xor(t, 2);
    h[o] = fmaxf(t + bA[o], 0.f);
  }
  // layer 2: this lane produces o2 = cq*8 .. cq*8+7
  unsigned int pk[4];
#pragma unroll
  for (int oo = 0; oo < 8; oo += 2) {
    int o2 = cq * 8 + oo;
    float s0 = bB[o2], s1 = bB[o2 + 1];
    const float* w0 = wB + (size_t)o2 * 32;
    const float* w1 = wB + (size_t)(o2 + 1) * 32;
#pragma unroll
    for (int i4 = 0; i4 < 8; ++i4) {
      f32x4 a = *(const f32x4*)(w0 + i4 * 4);
      f32x4 c = *(const f32x4*)(w1 + i4 * 4);
#pragma unroll
      for (int r = 0; r < 4; ++r) {
        s0 += a[r] * h[i4 * 4 + r];
        s1 += c[r] * h[i4 * 4 + r];
      }
    }
    if (p == 0) { s0 *= LOG2E; s1 *= LOG2E; }
    pk[oo >> 1] = (unsigned int)f2bf(s0) | ((unsigned int)f2bf(s1) << 16);
  }
  uint2v v0 = {pk[0], pk[1]};
  uint2v v1 = {pk[2], pk[3]};
  unsigned short* dst = (p ? kT : qT) + (size_t)n * 32 + cq * 8;
  *(uint2v*)(dst) = v0;
  *(uint2v*)(dst + 4) = v1;
}

// ---------------- kernel 2: flash attention, split-K over m, no V staging
// V fragments read directly from L2-resident Fbf. 1 barrier per m-tile.
__global__ __launch_bounds__(256, 4) void k_attn(
    const unsigned short* __restrict__ qT,
    const unsigned short* __restrict__ kT,
    const unsigned short* __restrict__ Fbf,
    const float* __restrict__ F,
    float* __restrict__ out,
    float* __restrict__ Opart,
    float* __restrict__ Mpart,
    float* __restrict__ Lpart,
    int spl, int mtiles, int direct) {
  __shared__ unsigned short Pb[2][64 * MT];   // 8 KB, xor-swizzled
  __shared__ float scl[2][64];

  const int tid = threadIdx.x;
  const int w = tid >> 6, lane = tid & 63, lo = lane & 15, hi = lane >> 4;
  const int sx = (lo & 3) ^ ((lo >> 2) & 3);   // bank swizzle key

  const int bid = (int)blockIdx.x;
  int g, ns;
  if (spl == 4)      { g = ((bid & 7) << 1) | (bid >> 9); ns = (bid >> 3) & 63; }
  else if (spl == 2) { g = bid & 7;                       ns = bid >> 3; }
  else               { int sz = (bid & 7) * 32 + (bid >> 3); g = sz >> 6; ns = sz & 63; }
  const int b = (spl == 4) ? (g >> 2) : ((spl == 2) ? (g >> 1) : g);
  const int s = (spl == 4) ? (g & 3) : ((spl == 2) ? (g & 1) : 0);
  const int n0 = ns << 6;
  const int mt0 = s * mtiles;

  const bf16x8 qfrag = *(const bf16x8*)(
      qT + ((size_t)(b << 12) + n0 + (w << 4) + lo) * 32 + (hi << 3));
  const unsigned short* kTb = kT + ((size_t)(b << 12)) * 32;
  const unsigned short* Fb = Fbf + ((size_t)b << 20);

  f32x4 acc[4][4];
#pragma unroll
  for (int i = 0; i < 4; ++i)
#pragma unroll
    for (int j = 0; j < 4; ++j) acc[i][j] = (f32x4){0.f, 0.f, 0.f, 0.f};
  float mrun = -INFINITY, lrun = 0.f;

  bf16x8 kc0 = *(const bf16x8*)(kTb + ((size_t)((mt0 << 5) + lo)) * 32 + (hi << 3));
  bf16x8 kc1 = *(const bf16x8*)(kTb + ((size_t)((mt0 << 5) + 16 + lo)) * 32 + (hi << 3));

  for (int t = 0; t < mtiles; ++t) {
    // V fragments for tile t: direct from L2 (issued first, consumed after barrier)
    bf16x8 vf[4];
#pragma unroll
    for (int cs2 = 0; cs2 < 4; ++cs2) {
      int c = (w << 6) + (cs2 << 4) + lo;
      vf[cs2] = *(const bf16x8*)(Fb + (size_t)c * 4096 + ((mt0 + t) << 5) + (hi << 3));
    }
    // QK^T
    f32x4 z = (f32x4){0.f, 0.f, 0.f, 0.f};
    f32x4 s0 = __builtin_amdgcn_mfma_f32_16x16x32_bf16(kc0, qfrag, z, 0, 0, 0);
    f32x4 s1 = __builtin_amdgcn_mfma_f32_16x16x32_bf16(kc1, qfrag, z, 0, 0, 0);
    // K prefetch t+1
    if (t + 1 < mtiles) {
      int mo = (mt0 + t + 1) << 5;
      kc0 = *(const bf16x8*)(kTb + ((size_t)(mo + lo)) * 32 + (hi << 3));
      kc1 = *(const bf16x8*)(kTb + ((size_t)(mo + 16 + lo)) * 32 + (hi << 3));
    }
    // online softmax (lane owns q = n0+16w+lo; m-values in s0/s1 regs)
    float tmax = fmaxf(fmaxf(fmaxf(s0[0], s0[1]), fmaxf(s0[2], s0[3])),
                       fmaxf(fmaxf(s1[0], s1[1]), fmaxf(s1[2], s1[3])));
    tmax = fmaxf(tmax, __shfl_xor(tmax, 16));
    tmax = fmaxf(tmax, __shfl_xor(tmax, 32));
    float mnew = fmaxf(mrun, tmax);
    float sc = exp2f(mrun - mnew);
    mrun = mnew;
    float p00 = exp2f(s0[0] - mnew), p01 = exp2f(s0[1] - mnew);
    float p02 = exp2f(s0[2] - mnew), p03 = exp2f(s0[3] - mnew);
    float p10 = exp2f(s1[0] - mnew), p11 = exp2f(s1[1] - mnew);
    float p12 = exp2f(s1[2] - mnew), p13 = exp2f(s1[3] - mnew);
    float rsum = p00 + p01 + p02 + p03 + p10 + p11 + p12 + p13;
    rsum += __shfl_xor(rsum, 16);
    rsum += __shfl_xor(rsum, 32);
    lrun = lrun * sc + rsum;
    if (hi == 0) scl[t & 1][(w << 4) + lo] = sc;
    {
      const int qr = (w << 4) + lo;
      unsigned short* base = &Pb[t & 1][qr * MT];
      int ph0 = (hi >> 1) ^ sx;
      int ph1 = (2 + (hi >> 1)) ^ sx;
      uint2v v0 = {(unsigned int)f2bf(p00) | ((unsigned int)f2bf(p01) << 16),
                   (unsigned int)f2bf(p02) | ((unsigned int)f2bf(p03) << 16)};
      uint2v v1 = {(unsigned int)f2bf(p10) | ((unsigned int)f2bf(p11) << 16),
                   (unsigned int)f2bf(p12) | ((unsigned int)f2bf(p13) << 16)};
      *(uint2v*)(base + ((ph0 << 3) | ((hi & 1) << 2))) = v0;
      *(uint2v*)(base + ((ph1 << 3) | ((hi & 1) << 2))) = v1;
    }

    __syncthreads();   // P/scl(t) visible; prev readers done (parity dbuf)

    // rescale (skip when all scales == 1)
    {
      f32x4 sv[4];
      bool one = true;
#pragma unroll
      for (int qf = 0; qf < 4; ++qf) {
        sv[qf] = *(const f32x4*)&scl[t & 1][(qf << 4) + (hi << 2)];
        one = one && (sv[qf][0] == 1.f) && (sv[qf][1] == 1.f) &&
              (sv[qf][2] == 1.f) && (sv[qf][3] == 1.f);
      }
      if (!__all(one)) {
#pragma unroll
        for (int qf = 0; qf < 4; ++qf)
#pragma unroll
          for (int cs2 = 0; cs2 < 4; ++cs2) acc[qf][cs2] *= sv[qf];
      }
    }
    // PV
    bf16x8 pf[4];
#pragma unroll
    for (int qf = 0; qf < 4; ++qf) {
      int qr = (qf << 4) + lo;
      pf[qf] = *(const bf16x8*)&Pb[t & 1][qr * MT + (((hi ^ sx) << 3))];
    }
    __builtin_amdgcn_s_setprio(1);
#pragma unroll
    for (int qf = 0; qf < 4; ++qf)
#pragma unroll
      for (int cs2 = 0; cs2 < 4; ++cs2)
        acc[qf][cs2] = __builtin_amdgcn_mfma_f32_16x16x32_bf16(pf[qf], vf[cs2], acc[qf][cs2], 0, 0, 0);
    __builtin_amdgcn_s_setprio(0);
  }

  if (direct) {
    if (hi == 0) scl[0][(w << 4) + lo] = 1.f / lrun;
    __syncthreads();
    f32x4 lv[4];
#pragma unroll
    for (int qf = 0; qf < 4; ++qf) lv[qf] = *(const f32x4*)&scl[0][(qf << 4) + (hi << 2)];
#pragma unroll
    for (int qf = 0; qf < 4; ++qf)
#pragma unroll
      for (int cs2 = 0; cs2 < 4; ++cs2) {
        size_t idx = ((size_t)(b * 256 + (w << 6) + (cs2 << 4) + lo)) * 4096 +
                     n0 + (qf << 4) + (hi << 2);
        f32x4 fv = *(const f32x4*)(F + idx);
        *(f32x4*)(out + idx) = fv + acc[qf][cs2] * lv[qf];
      }
  } else {
    const int bp = (b * spl + s) * 64 + ns;
    if (hi == 0) {
      Mpart[bp * 64 + (w << 4) + lo] = mrun;
      Lpart[bp * 64 + (w << 4) + lo] = lrun;
    }
    float* Ob = Opart + (size_t)bp * 256 * 64;
#pragma unroll
    for (int qf = 0; qf < 4; ++qf)
#pragma unroll
      for (int cs2 = 0; cs2 < 4; ++cs2) {
        int c = (w << 6) + (cs2 << 4) + lo;
        *(f32x4*)(Ob + (size_t)c * 64 + (qf << 4) + (hi << 2)) = acc[qf][cs2];
      }
  }
}

// ---------------- kernel 3: combine split partials + residual
__global__ __launch_bounds__(256, 4) void k_comb(
    const float* __restrict__ F, const float* __restrict__ Opart,
    const float* __restrict__ Mpart, const float* __restrict__ Lpart,
    float* __restrict__ out, int spl) {
  __shared__ float a[4][64];
  const int cid = (int)blockIdx.x;           // 1024
  const int b = cid >> 8, ns = (cid >> 2) & 63, cq = cid & 3;
  const int tid = threadIdx.x, q = tid & 63, ci = tid >> 6;
  const int n0 = ns << 6;

  if (tid < 64) {
    float mv[4], lv[4];
    float M = -INFINITY;
#pragma unroll
    for (int s2 = 0; s2 < 4; ++s2)
      if (s2 < spl) {
        int bp = (b * spl + s2) * 64 + ns;
        mv[s2] = Mpart[bp * 64 + q];
        lv[s2] = Lpart[bp * 64 + q];
        M = fmaxf(M, mv[s2]);
      }
    float L = 0.f;
#pragma unroll
    for (int s2 = 0; s2 < 4; ++s2)
      if (s2 < spl) { mv[s2] = exp2f(mv[s2] - M); L += mv[s2] * lv[s2]; }
    float Li = 1.f / L;
#pragma unroll
    for (int s2 = 0; s2 < 4; ++s2)
      if (s2 < spl) a[s2][q] = mv[s2] * Li;
  }
  __syncthreads();
  float aq[4];
#pragma unroll
  for (int s2 = 0; s2 < 4; ++s2) aq[s2] = (s2 < spl) ? a[s2][q] : 0.f;

#pragma unroll 4
  for (int cc = 0; cc < 16; ++cc) {
    int c = (cq << 6) + (ci << 4) + cc;
    float accv = 0.f;
#pragma unroll
    for (int s2 = 0; s2 < 4; ++s2)
      if (s2 < spl)
        accv += aq[s2] * Opart[((size_t)((b * spl + s2) * 64 + ns) * 256 + c) * 64 + q];
    size_t idx = ((size_t)(b * 256 + c)) * 4096 + n0 + q;
    out[idx] = F[idx] + accv;
  }
}

extern "C" void kernel_launch(void* const* d_in, const int* in_sizes, int n_in,
                              void* d_out, int out_size, void* d_ws, size_t ws_size,
                              hipStream_t stream) {
  const float* F   = (const float*)d_in[0];
  const float* w1a = (const float*)d_in[1];
  const float* b1a = (const float*)d_in[2];
  const float* w1b = (const float*)d_in[3];
  const float* b1b = (const float*)d_in[4];
  const float* w2a = (const float*)d_in[5];
  const float* b2a = (const float*)d_in[6];
  const float* w2b = (const float*)d_in[7];
  const float* b2b = (const float*)d_in[8];
  float* out = (float*)d_out;

  char* ws = (char*)d_ws;
  float* w1aT = (float*)(ws);
  float* w2aT = (float*)(ws + 32768);
  unsigned short* qT  = (unsigned short*)(ws + 65536);
  unsigned short* kT  = (unsigned short*)(ws + 65536 + 1048576);
  unsigned short* Fbf = (unsigned short*)(ws + 65536 + 2097152);
  const size_t obase = 65536 + 2097152 + 8388608;               // 10,551,296

  // FbfT aliases the Opart region: read (k_qk) strictly before Opart writes (k_attn).
  unsigned short* FbfT = (unsigned short*)(ws + obase);

  int spl = 1, direct = 1;
  const size_t oSz1 = 16777216, mlSz1 = 65536;
  if (ws_size >= obase + 4 * (oSz1 + 2 * mlSz1)) { spl = 4; direct = 0; }
  else if (ws_size >= obase + 2 * (oSz1 + 2 * mlSz1)) { spl = 2; direct = 0; }

  float* Opart = (float*)(ws + obase);
  float* Mpart = (float*)(ws + obase + (size_t)spl * oSz1);
  float* Lpart = (float*)(ws + obase + (size_t)spl * oSz1 + (size_t)spl * mlSz1);

  hipLaunchKernelGGL(k_wprep, dim3(32), dim3(256), 0, stream, w1a, w2a, w1aT, w2aT);
  hipLaunchKernelGGL(k_cvt, dim3(1024), dim3(256), 0, stream, F, Fbf, FbfT);
  hipLaunchKernelGGL(k_qk, dim3(2048), dim3(64), 0, stream,
                     FbfT, w1aT, b1a, w1b, b1b, w2aT, b2a, w2b, b2b, qT, kT);
  hipLaunchKernelGGL(k_attn, dim3(256 * spl), dim3(256), 0, stream,
                     qT, kT, Fbf, F, out, Opart, Mpart, Lpart, spl, 128 / spl, direct);
  if (!direct)
    hipLaunchKernelGGL(k_comb, dim3(1024), dim3(256), 0, stream,
                       F, Opart, Mpart, Lpart, out, spl);
}

// Round 6
// 318.161 us; speedup vs baseline: 1.1318x; 1.1318x over previous
//
#include <hip/hip_runtime.h>
#include <hip/hip_bf16.h>
#include <math.h>

typedef __attribute__((ext_vector_type(4))) float f32x4;
typedef __attribute__((ext_vector_type(16))) float f32x16;
typedef __attribute__((ext_vector_type(8))) short bf16x8;
typedef __attribute__((ext_vector_type(2))) unsigned int uint2v;
typedef __attribute__((ext_vector_type(4))) unsigned int uint4v;

#define LOG2E 1.4426950408889634f

static __device__ __forceinline__ unsigned short f2bf(float f) {
  union { float f; unsigned int i; } u; u.f = f;
  unsigned int r = u.i + 0x7fffu + ((u.i >> 16) & 1u);   // RNE
  return (unsigned short)(r >> 16);
}
static __device__ __forceinline__ float bf2f(unsigned short s) {
  union { unsigned int i; float f; } u; u.i = ((unsigned int)s) << 16;
  return u.f;
}
static __device__ __forceinline__ unsigned int pkbf(float a, float b) {
  return (unsigned int)f2bf(a) | ((unsigned int)f2bf(b) << 16);
}
static __device__ __forceinline__ bf16x8 mk8(uint2v a, uint2v b) {
  union { unsigned int u[4]; bf16x8 v; } c;
  c.u[0] = a[0]; c.u[1] = a[1]; c.u[2] = b[0]; c.u[3] = b[1];
  return c.v;
}
static __device__ __forceinline__ f32x16 zero16() {
  f32x16 z;
#pragma unroll
  for (int i = 0; i < 16; ++i) z[i] = 0.f;
  return z;
}

// ---------------- kernel 0: weights -> bf16 hi/lo splits (layouts unchanged)
__global__ __launch_bounds__(256) void k_wprep(
    const float* __restrict__ w1a, const float* __restrict__ w2a,
    const float* __restrict__ w1b, const float* __restrict__ w2b,
    unsigned short* __restrict__ w1ah, unsigned short* __restrict__ w1al,
    unsigned short* __restrict__ w2ah, unsigned short* __restrict__ w2al,
    unsigned short* __restrict__ w1bh, unsigned short* __restrict__ w1bl,
    unsigned short* __restrict__ w2bh, unsigned short* __restrict__ w2bl) {
  int i = blockIdx.x * 256 + threadIdx.x;
  if (i < 8192) {
    float a = w1a[i]; unsigned short h = f2bf(a);
    w1ah[i] = h; w1al[i] = f2bf(a - bf2f(h));
    float c = w2a[i]; h = f2bf(c);
    w2ah[i] = h; w2al[i] = f2bf(c - bf2f(h));
    if (i < 1024) {
      float d = w1b[i]; h = f2bf(d);
      w1bh[i] = h; w1bl[i] = f2bf(d - bf2f(h));
      float e = w2b[i]; h = f2bf(e);
      w2bh[i] = h; w2bl[i] = f2bf(e - bf2f(h));
    }
  }
}

// ---------------- kernel 0b: F -> Fbf [c][n] and FbfT [n][c] (bf16)
__global__ __launch_bounds__(256) void k_cvt(const float* __restrict__ F,
                                             unsigned short* __restrict__ Fbf,
                                             unsigned short* __restrict__ FbfT) {
  __shared__ unsigned short Lt[64][68];
  const int bi = blockIdx.x;
  const int b = bi >> 8, cg = (bi >> 6) & 3, ng = bi & 63;
  const int tid = threadIdx.x;
  {
    const int cl = tid >> 2, part = tid & 3;
    const size_t row = (size_t)(b * 256 + cg * 64 + cl);
    const float* src = F + row * 4096 + ng * 64 + part * 16;
    unsigned int pk[8];
#pragma unroll
    for (int i = 0; i < 4; ++i) {
      f32x4 v = *(const f32x4*)(src + i * 4);
      pk[2 * i]     = pkbf(v[0], v[1]);
      pk[2 * i + 1] = pkbf(v[2], v[3]);
    }
    unsigned short* dst = Fbf + row * 4096 + ng * 64 + part * 16;
    uint4v a = {pk[0], pk[1], pk[2], pk[3]};
    uint4v c2 = {pk[4], pk[5], pk[6], pk[7]};
    *(uint4v*)(dst) = a;
    *(uint4v*)(dst + 8) = c2;
    unsigned short* lrow = &Lt[cl][part * 16];
#pragma unroll
    for (int i = 0; i < 8; ++i) {
      lrow[2 * i]     = (unsigned short)(pk[i] & 0xffffu);
      lrow[2 * i + 1] = (unsigned short)(pk[i] >> 16);
    }
  }
  __syncthreads();
  {
    const int nl = tid & 63, ch = tid >> 6;
    unsigned short vals[16];
#pragma unroll
    for (int i = 0; i < 16; ++i) vals[i] = Lt[ch * 16 + i][nl];
    unsigned int pk[8];
#pragma unroll
    for (int i = 0; i < 8; ++i)
      pk[i] = (unsigned int)vals[2 * i] | ((unsigned int)vals[2 * i + 1] << 16);
    unsigned short* dst = FbfT + ((size_t)(b * 4096 + ng * 64 + nl)) * 256 + cg * 64 + ch * 16;
    uint4v v0 = {pk[0], pk[1], pk[2], pk[3]};
    uint4v v1 = {pk[4], pk[5], pk[6], pk[7]};
    *(uint4v*)(dst) = v0;
    *(uint4v*)(dst + 8) = v1;
  }
}

// ---------------- kernel 1: q/k projections via MFMA, split-bf16 weights
// 512 blocks x 256 thr: block = (path, 64-px tile), wave = 16 px.
__global__ __launch_bounds__(256, 4) void k_qk(
    const unsigned short* __restrict__ FbfT,
    const unsigned short* __restrict__ w1ah, const unsigned short* __restrict__ w1al,
    const unsigned short* __restrict__ w2ah, const unsigned short* __restrict__ w2al,
    const unsigned short* __restrict__ w1bh, const unsigned short* __restrict__ w1bl,
    const unsigned short* __restrict__ w2bh, const unsigned short* __restrict__ w2bl,
    const float* __restrict__ b1a, const float* __restrict__ b1b,
    const float* __restrict__ b2a, const float* __restrict__ b2b,
    unsigned short* __restrict__ qT, unsigned short* __restrict__ kT) {
  __shared__ unsigned short Hb[4][2][16][32];   // per-wave h hi/lo, swizzled
  const int tid = threadIdx.x;
  const int w = tid >> 6, lane = tid & 63, lo = lane & 15, hi = lane >> 4;
  const int p = blockIdx.x & 1;
  const int nb = (blockIdx.x >> 1) * 64 + w * 16;
  const unsigned short* wah = p ? w2ah : w1ah;
  const unsigned short* wal = p ? w2al : w1al;
  const unsigned short* wbh = p ? w2bh : w1bh;
  const unsigned short* wbl = p ? w2bl : w1bl;
  const float* bA = p ? b2a : b1a;
  const float* bB = p ? b2b : b1b;
  const int gq = (lo >> 1) & 7;

  // layer 1: acc[m] over K=256 (8 steps), A = W (hi+lo), B = F
  f32x4 acc[2];
#pragma unroll
  for (int m = 0; m < 2; ++m) acc[m] = (f32x4){0.f, 0.f, 0.f, 0.f};
#pragma unroll
  for (int ks = 0; ks < 8; ++ks) {
    bf16x8 bf = *(const bf16x8*)(FbfT + (size_t)(nb + lo) * 256 + ks * 32 + hi * 8);
#pragma unroll
    for (int m = 0; m < 2; ++m) {
      bf16x8 ah = *(const bf16x8*)(wah + (size_t)(m * 16 + lo) * 256 + ks * 32 + hi * 8);
      bf16x8 al = *(const bf16x8*)(wal + (size_t)(m * 16 + lo) * 256 + ks * 32 + hi * 8);
      acc[m] = __builtin_amdgcn_mfma_f32_16x16x32_bf16(ah, bf, acc[m], 0, 0, 0);
      acc[m] = __builtin_amdgcn_mfma_f32_16x16x32_bf16(al, bf, acc[m], 0, 0, 0);
    }
  }
  // bias + relu + hi/lo split -> per-wave LDS (swizzled 8B chunks)
#pragma unroll
  for (int m = 0; m < 2; ++m) {
    f32x4 bv = *(const f32x4*)(bA + m * 16 + hi * 4);
    float hh[4], hl[4];
#pragma unroll
    for (int r = 0; r < 4; ++r) {
      float h = fmaxf(acc[m][r] + bv[r], 0.f);
      unsigned short s16 = f2bf(h);
      hh[r] = bf2f(s16);
      hl[r] = h - hh[r];
    }
    int c8 = (4 * m + hi) ^ gq;
    uint2v vh = {pkbf(hh[0], hh[1]), pkbf(hh[2], hh[3])};
    uint2v vl = {pkbf(hl[0], hl[1]), pkbf(hl[2], hl[3])};
    *(uint2v*)&Hb[w][0][lo][c8 * 4] = vh;
    *(uint2v*)&Hb[w][1][lo][c8 * 4] = vl;
  }
  // read h as B-fragments (same wave; compiler orders via lgkmcnt)
  bf16x8 hbf[2];
#pragma unroll
  for (int sp = 0; sp < 2; ++sp) {
    uint2v ra = *(const uint2v*)&Hb[w][sp][lo][((2 * hi) ^ gq) * 4];
    uint2v rb = *(const uint2v*)&Hb[w][sp][lo][((2 * hi + 1) ^ gq) * 4];
    hbf[sp] = mk8(ra, rb);
  }
  // layer 2 (K=32, one step; 3 split terms)
  f32x4 a2[2];
#pragma unroll
  for (int m = 0; m < 2; ++m) a2[m] = (f32x4){0.f, 0.f, 0.f, 0.f};
#pragma unroll
  for (int m = 0; m < 2; ++m) {
    bf16x8 ah = *(const bf16x8*)(wbh + (size_t)(m * 16 + lo) * 32 + hi * 8);
    bf16x8 al = *(const bf16x8*)(wbl + (size_t)(m * 16 + lo) * 32 + hi * 8);
    a2[m] = __builtin_amdgcn_mfma_f32_16x16x32_bf16(ah, hbf[0], a2[m], 0, 0, 0);
    a2[m] = __builtin_amdgcn_mfma_f32_16x16x32_bf16(ah, hbf[1], a2[m], 0, 0, 0);
    a2[m] = __builtin_amdgcn_mfma_f32_16x16x32_bf16(al, hbf[0], a2[m], 0, 0, 0);
  }
  unsigned short* dst = (p ? kT : qT) + (size_t)(nb + lo) * 32;
#pragma unroll
  for (int m = 0; m < 2; ++m) {
    f32x4 bv = *(const f32x4*)(bB + m * 16 + hi * 4);
    float o[4];
#pragma unroll
    for (int r = 0; r < 4; ++r) {
      o[r] = a2[m][r] + bv[r];
      if (p == 0) o[r] *= LOG2E;    // q in exp2 domain
    }
    uint2v v = {pkbf(o[0], o[1]), pkbf(o[2], o[3])};
    *(uint2v*)(dst + m * 16 + hi * 4) = v;
  }
}

// ---------------- kernel 2: barrier-free flash attention, 32x32 MFMA
// Block (b, s, qt): 64 q-rows; wave w owns c in [64w,64w+64); all waves
// duplicate QK^T+softmax for all 64 q. V direct from L2. NO __syncthreads.
__global__ __launch_bounds__(256, 3) void k_attn(
    const unsigned short* __restrict__ qT,
    const unsigned short* __restrict__ kT,
    const unsigned short* __restrict__ Fbf,
    const float* __restrict__ F,
    float* __restrict__ out,
    float* __restrict__ Opart, float* __restrict__ Mpart, float* __restrict__ Lpart,
    int spl, int tiles, int direct) {
  __shared__ unsigned short PbA[4][1024];   // per-wave P buffer (2KB), swizzled
  __shared__ float sclA[4][64];             // per-wave scale/linv broadcast
  const int tid = threadIdx.x;
  const int w = tid >> 6, lane = tid & 63, l31 = lane & 31, b5 = lane >> 5;
  unsigned short* Pb = PbA[w];
  float* scl = sclA[w];
  const int g = (l31 >> 1) & 7;

  const int bid = (int)blockIdx.x;
  int b, s, qt;
  if (spl == 4)      { int gg = ((bid & 7) << 1) | (bid >> 9); b = gg >> 2; s = gg & 3; qt = (bid >> 3) & 63; }
  else if (spl == 2) { int gg = bid & 7; b = gg >> 1; s = gg & 1; qt = bid >> 3; }
  else               { int x = bid & 7; b = x >> 1; s = 0; qt = ((x & 1) << 5) | (bid >> 3); }

  const unsigned short* qTb = qT + ((size_t)(b << 12) + qt * 64) * 32;
  const unsigned short* kTb = kT + ((size_t)(b << 12)) * 32;
  const unsigned short* Fb  = Fbf + ((size_t)b << 20);
  const int cb = w << 6;
  const int mt0 = s * tiles;

  // loop-invariant Q fragments [q-tile][k-slice]
  bf16x8 qf[2][2];
#pragma unroll
  for (int q2 = 0; q2 < 2; ++q2)
#pragma unroll
    for (int sl = 0; sl < 2; ++sl)
      qf[q2][sl] = *(const bf16x8*)(qTb + (size_t)(q2 * 32 + l31) * 32 + sl * 16 + b5 * 8);

  f32x16 acc[2][2];   // [q-tile][c-tile]
#pragma unroll
  for (int i = 0; i < 2; ++i)
#pragma unroll
    for (int j = 0; j < 2; ++j) acc[i][j] = zero16();
  float mrun[2] = {-INFINITY, -INFINITY};
  float lrun[2] = {0.f, 0.f};

  bf16x8 kc0 = *(const bf16x8*)(kTb + (size_t)((mt0 << 5) + l31) * 32 + b5 * 8);
  bf16x8 kc1 = *(const bf16x8*)(kTb + (size_t)((mt0 << 5) + l31) * 32 + 16 + b5 * 8);

  for (int t = 0; t < tiles; ++t) {
    const int m0 = (mt0 + t) << 5;
    // V fragments direct from L2 (issued early, consumed after softmax)
    bf16x8 vf[2][2];
#pragma unroll
    for (int ct = 0; ct < 2; ++ct)
#pragma unroll
      for (int sl = 0; sl < 2; ++sl)
        vf[ct][sl] = *(const bf16x8*)(Fb + (size_t)(cb + ct * 32 + l31) * 4096 + m0 + sl * 16 + b5 * 8);
    // K prefetch (clamped address, no branch)
    const int m1 = (t + 1 < tiles) ? (m0 + 32) : m0;
    bf16x8 kn0 = *(const bf16x8*)(kTb + (size_t)(m1 + l31) * 32 + b5 * 8);
    bf16x8 kn1 = *(const bf16x8*)(kTb + (size_t)(m1 + l31) * 32 + 16 + b5 * 8);

#pragma unroll
    for (int q2 = 0; q2 < 2; ++q2) {
      // S^T = K·Q: lane owns q-col = l31; rows m = (r&3)+8(r>>2)+4*b5
      f32x16 S = __builtin_amdgcn_mfma_f32_32x32x16_bf16(kc0, qf[q2][0], zero16(), 0, 0, 0);
      S = __builtin_amdgcn_mfma_f32_32x32x16_bf16(kc1, qf[q2][1], S, 0, 0, 0);
      float tmax = S[0];
#pragma unroll
      for (int i = 1; i < 16; ++i) tmax = fmaxf(tmax, S[i]);
      tmax = fmaxf(tmax, __shfl_xor(tmax, 32));
      // defer-max (T13): rescale only when max grows past threshold
      if (__any(tmax - mrun[q2] > 8.f)) {
        float mnew = fmaxf(mrun[q2], tmax);
        float sc = exp2f(mrun[q2] - mnew);
        mrun[q2] = mnew;
        lrun[q2] *= sc;
        scl[q2 * 32 + l31] = sc;
#pragma unroll
        for (int u = 0; u < 4; ++u) {
          f32x4 sv = *(const f32x4*)&scl[q2 * 32 + u * 8 + b5 * 4];
#pragma unroll
          for (int r = 0; r < 4; ++r) {
            acc[q2][0][u * 4 + r] *= sv[r];
            acc[q2][1][u * 4 + r] *= sv[r];
          }
        }
      }
      float pv[16];
      float rs = 0.f;
#pragma unroll
      for (int i = 0; i < 16; ++i) { pv[i] = exp2f(S[i] - mrun[q2]); rs += pv[i]; }
      rs += __shfl_xor(rs, 32);
      lrun[q2] += rs;
      // P -> per-wave LDS (reg quad u holds m = 8u+4*b5 .. +3)
#pragma unroll
      for (int u = 0; u < 4; ++u) {
        uint2v pw = {pkbf(pv[4 * u], pv[4 * u + 1]), pkbf(pv[4 * u + 2], pv[4 * u + 3])};
        *(uint2v*)&Pb[l31 * 32 + (((2 * u + b5) ^ g) << 2)] = pw;
      }
      // A-fragments: slice sl needs m = 16sl + 8*b5 .. +7
      bf16x8 pa[2];
#pragma unroll
      for (int sl = 0; sl < 2; ++sl) {
        uint2v ra = *(const uint2v*)&Pb[l31 * 32 + (((4 * sl + 2 * b5) ^ g) << 2)];
        uint2v rb = *(const uint2v*)&Pb[l31 * 32 + (((4 * sl + 2 * b5 + 1) ^ g) << 2)];
        pa[sl] = mk8(ra, rb);
      }
#pragma unroll
      for (int ct = 0; ct < 2; ++ct) {
        acc[q2][ct] = __builtin_amdgcn_mfma_f32_32x32x16_bf16(pa[0], vf[ct][0], acc[q2][ct], 0, 0, 0);
        acc[q2][ct] = __builtin_amdgcn_mfma_f32_32x32x16_bf16(pa[1], vf[ct][1], acc[q2][ct], 0, 0, 0);
      }
    }
    kc0 = kn0; kc1 = kn1;
  }

  if (direct) {
#pragma unroll
    for (int q2 = 0; q2 < 2; ++q2) scl[q2 * 32 + l31] = 1.f / lrun[q2];
#pragma unroll
    for (int q2 = 0; q2 < 2; ++q2)
#pragma unroll
      for (int ct = 0; ct < 2; ++ct) {
        const int c = cb + ct * 32 + l31;
#pragma unroll
        for (int u = 0; u < 4; ++u) {
          f32x4 lv = *(const f32x4*)&scl[q2 * 32 + u * 8 + b5 * 4];
          size_t idx = ((size_t)(b * 256 + c)) * 4096 + qt * 64 + q2 * 32 + u * 8 + b5 * 4;
          f32x4 fv = *(const f32x4*)(F + idx);
          f32x4 o;
#pragma unroll
          for (int r = 0; r < 4; ++r) o[r] = fv[r] + acc[q2][ct][u * 4 + r] * lv[r];
          *(f32x4*)(out + idx) = o;
        }
      }
  } else {
    const int bp = (b * spl + s) * 64 + qt;
    if (w == 0 && b5 == 0) {
#pragma unroll
      for (int q2 = 0; q2 < 2; ++q2) {
        Mpart[bp * 64 + q2 * 32 + l31] = mrun[q2];
        Lpart[bp * 64 + q2 * 32 + l31] = lrun[q2];
      }
    }
    float* Ob = Opart + (size_t)bp * 16384;
#pragma unroll
    for (int q2 = 0; q2 < 2; ++q2)
#pragma unroll
      for (int ct = 0; ct < 2; ++ct) {
        const int c = cb + ct * 32 + l31;
#pragma unroll
        for (int u = 0; u < 4; ++u) {
          f32x4 o;
#pragma unroll
          for (int r = 0; r < 4; ++r) o[r] = acc[q2][ct][u * 4 + r];
          *(f32x4*)(Ob + (size_t)c * 64 + q2 * 32 + u * 8 + b5 * 4) = o;
        }
      }
  }
}

// ---------------- kernel 3: combine split partials + residual
__global__ __launch_bounds__(256) void k_comb(
    const float* __restrict__ F, const float* __restrict__ Opart,
    const float* __restrict__ Mpart, const float* __restrict__ Lpart,
    float* __restrict__ out, int spl) {
  const int bid = (int)blockIdx.x;          // 256 = b*64 + qt
  const int b = bid >> 6, qt = bid & 63;
  const int tid = threadIdx.x, ql = tid & 63, cq = tid >> 6;
  float mv[4], lv[4];
  float M = -INFINITY;
#pragma unroll
  for (int s = 0; s < 4; ++s)
    if (s < spl) {
      int bp = (b * spl + s) * 64 + qt;
      mv[s] = Mpart[bp * 64 + ql];
      lv[s] = Lpart[bp * 64 + ql];
      M = fmaxf(M, mv[s]);
    }
  float L = 0.f;
#pragma unroll
  for (int s = 0; s < 4; ++s)
    if (s < spl) { mv[s] = exp2f(mv[s] - M); L += mv[s] * lv[s]; }
  float Li = 1.f / L;
  float a[4];
#pragma unroll
  for (int s = 0; s < 4; ++s) a[s] = (s < spl) ? mv[s] * Li : 0.f;

  for (int cc = 0; cc < 64; ++cc) {
    int c = cq * 64 + cc;
    float accv = 0.f;
#pragma unroll
    for (int s = 0; s < 4; ++s)
      if (s < spl)
        accv += a[s] * Opart[((size_t)((b * spl + s) * 64 + qt)) * 16384 + c * 64 + ql];
    size_t idx = ((size_t)(b * 256 + c)) * 4096 + qt * 64 + ql;
    out[idx] = F[idx] + accv;
  }
}

extern "C" void kernel_launch(void* const* d_in, const int* in_sizes, int n_in,
                              void* d_out, int out_size, void* d_ws, size_t ws_size,
                              hipStream_t stream) {
  const float* F   = (const float*)d_in[0];
  const float* w1a = (const float*)d_in[1];
  const float* b1a = (const float*)d_in[2];
  const float* w1b = (const float*)d_in[3];
  const float* b1b = (const float*)d_in[4];
  const float* w2a = (const float*)d_in[5];
  const float* b2a = (const float*)d_in[6];
  const float* w2b = (const float*)d_in[7];
  const float* b2b = (const float*)d_in[8];
  float* out = (float*)d_out;

  char* ws = (char*)d_ws;
  unsigned short* qTw = (unsigned short*)(ws);                 // 1 MB
  unsigned short* kTw = (unsigned short*)(ws + 1048576);       // 1 MB
  unsigned short* Fbf = (unsigned short*)(ws + 2097152);       // 8 MB
  const size_t obase = 10485760;
  // FbfT + weight splits alias Opart (both dead before k_attn writes Opart)
  unsigned short* FbfT = (unsigned short*)(ws + obase);        // 8 MB
  char* wreg = ws + obase + 8388608;
  unsigned short* w1ah = (unsigned short*)(wreg);
  unsigned short* w1al = (unsigned short*)(wreg + 16384);
  unsigned short* w2ah = (unsigned short*)(wreg + 32768);
  unsigned short* w2al = (unsigned short*)(wreg + 49152);
  unsigned short* w1bh = (unsigned short*)(wreg + 65536);
  unsigned short* w1bl = (unsigned short*)(wreg + 67584);
  unsigned short* w2bh = (unsigned short*)(wreg + 69632);
  unsigned short* w2bl = (unsigned short*)(wreg + 71680);

  int spl, direct = 0;
  if (ws_size >= obase + 4ull * 16777216 + 8ull * 65536)      spl = 4;
  else if (ws_size >= obase + 2ull * 16777216 + 4ull * 65536) spl = 2;
  else { spl = 1; direct = 1; }

  float* Opart = (float*)(ws + obase);
  float* Mpart = (float*)(ws + obase + (size_t)spl * 16777216);
  float* Lpart = (float*)(ws + obase + (size_t)spl * 16777216 + (size_t)spl * 65536);

  hipLaunchKernelGGL(k_wprep, dim3(32), dim3(256), 0, stream,
                     w1a, w2a, w1b, w2b,
                     w1ah, w1al, w2ah, w2al, w1bh, w1bl, w2bh, w2bl);
  hipLaunchKernelGGL(k_cvt, dim3(1024), dim3(256), 0, stream, F, Fbf, FbfT);
  hipLaunchKernelGGL(k_qk, dim3(512), dim3(256), 0, stream,
                     FbfT, w1ah, w1al, w2ah, w2al, w1bh, w1bl, w2bh, w2bl,
                     b1a, b1b, b2a, b2b, qTw, kTw);
  hipLaunchKernelGGL(k_attn, dim3(256 * spl), dim3(256), 0, stream,
                     qTw, kTw, Fbf, F, out, Opart, Mpart, Lpart, spl, 128 / spl, direct);
  if (!direct)
    hipLaunchKernelGGL(k_comb, dim3(256), dim3(256), 0, stream,
                       F, Opart, Mpart, Lpart, out, spl);
}